// Round 2
// baseline (199.256 us; speedup 1.0000x reference)
//
#include <hip/hip_runtime.h>

// NeRF positional encoding: x[rows,4] -> out[rows,768]
// Per row: 64-float block [sin(2^l*pi*x_c), cos(...)] for l=0..7, c=0..3,
// tiled 12x across 768 hidden dims. Purely write-BW bound (201 MB out, 1 MB in).
//
// One 64-lane wave per row. Lane i owns float4 chunk (i&15) of the 64-float
// block, computes its 2 sincos pairs once, and stores the same float4 at the
// 3 wave-strided chunk slots (192 chunks/row = 3 x 64 lanes).
//
// Stores are NON-TEMPORAL: the normal write-back/write-allocate L2 path does
// read-for-ownership on store miss, doubling HBM traffic (measured ~70 us
// ~= 402 MB @ 5.7 TB/s in round 1). `nt` streams the writes, ~33 us floor.

typedef float f32x4 __attribute__((ext_vector_type(4)));

__global__ __launch_bounds__(256) void nerf_pe_kernel(const float* __restrict__ x,
                                                      float* __restrict__ out,
                                                      int rows) {
    const int tid  = blockIdx.x * blockDim.x + threadIdx.x;
    const int row  = tid >> 6;      // one 64-lane wave per row
    const int lane = tid & 63;
    if (row >= rows) return;

    // chunk k = lane & 15 within the 64-float block:
    //   freq index l = k >> 1, coord pair base c = 2*(k & 1)
    const int   l = (lane & 15) >> 1;
    const bool  hi = (lane & 1);                            // c = 0 or 2
    const float f = 3.14159265358979f * (float)(1 << l);    // 2^l * pi

    // one broadcast 16B load per wave (all lanes same address)
    const f32x4 xr = *reinterpret_cast<const f32x4*>(x + (size_t)row * 4);
    const float x0 = hi ? xr.z : xr.x;
    const float x1 = hi ? xr.w : xr.y;
    const float a0 = f * x0;
    const float a1 = f * x1;

    f32x4 v;
    v.x = __sinf(a0);   // v_sin_f32 (revolutions internally; |a|/2pi <= 64, in range)
    v.y = __cosf(a0);
    v.z = __sinf(a1);
    v.w = __cosf(a1);

    // 192 float4 chunks per row; lane's chunk is valid at j = it*64 + lane,
    // it = 0..2 (j % 16 == lane % 16). 1 KiB contiguous per wave-store.
    f32x4* o = reinterpret_cast<f32x4*>(out + (size_t)row * 768) + lane;
    __builtin_nontemporal_store(v, o);
    __builtin_nontemporal_store(v, o + 64);
    __builtin_nontemporal_store(v, o + 128);
}

extern "C" void kernel_launch(void* const* d_in, const int* in_sizes, int n_in,
                              void* d_out, int out_size, void* d_ws, size_t ws_size,
                              hipStream_t stream) {
    const float* x   = (const float*)d_in[0];
    float*       out = (float*)d_out;
    const int rows    = in_sizes[0] / 4;          // 65536
    const int threads = rows * 64;                // one wave per row
    const int blocks  = (threads + 255) / 256;
    nerf_pe_kernel<<<blocks, 256, 0, stream>>>(x, out, rows);
}

// Round 3
// 192.282 us; speedup vs baseline: 1.0363x; 1.0363x over previous
//
#include <hip/hip_runtime.h>

// NeRF positional encoding: x[rows,4] -> out[rows,768]
// Per row: 64-float block [sin(2^l*pi*x_c), cos(...)] l=0..7, c=0..3, tiled 12x.
// Mandatory traffic: 192 MB write / 1 MB read -> ~31 us floor @ 6.3 TB/s.
//
// Round-2 post-mortem: kernel portion ~40 us (bench dur = big ws poison fill
// ~125 us + out poison ~31 us + kernel). Gap to floor is per-wave ramp, not
// RFO (1 KiB contiguous wave-stores fully cover lines; nt was neutral).
// This version: 8 rows per wave, all 8 broadcast x-loads prefetched before
// first use (loads pipeline under vmcnt), 24 dwordx4 stores per wave over a
// contiguous 24 KB span. 8192 waves = 32 waves/CU = full occupancy.

typedef float f32x4 __attribute__((ext_vector_type(4)));

constexpr int ROWS_PER_WAVE = 8;

__global__ __launch_bounds__(256) void nerf_pe_kernel(const float* __restrict__ x,
                                                      float* __restrict__ out,
                                                      int rows) {
    const int wave = (blockIdx.x * 256 + threadIdx.x) >> 6;
    const int lane = threadIdx.x & 63;
    const int r0   = wave * ROWS_PER_WAVE;
    if (r0 >= rows) return;

    // chunk k = lane & 15 of the 64-float block: freq l = k>>1, coord pair k&1
    const int   l  = (lane & 15) >> 1;
    const bool  hi = (lane & 1);
    const float f  = 3.14159265358979f * (float)(1 << l);   // 2^l * pi

    // prefetch all 8 row coords (broadcast 16B loads, issued back-to-back)
    f32x4 xr[ROWS_PER_WAVE];
#pragma unroll
    for (int i = 0; i < ROWS_PER_WAVE; ++i)
        xr[i] = *reinterpret_cast<const f32x4*>(x + (size_t)(r0 + i) * 4);

#pragma unroll
    for (int i = 0; i < ROWS_PER_WAVE; ++i) {
        const float x0 = hi ? xr[i].z : xr[i].x;
        const float x1 = hi ? xr[i].w : xr[i].y;
        f32x4 v;
        v.x = __sinf(f * x0);   // v_sin_f32; |angle|/2pi <= 64 rev, in HW range
        v.y = __cosf(f * x0);
        v.z = __sinf(f * x1);
        v.w = __cosf(f * x1);

        // 192 float4 chunks per row; lane's chunk valid at j = it*64 + lane
        f32x4* o = reinterpret_cast<f32x4*>(out + (size_t)(r0 + i) * 768) + lane;
        o[0]   = v;
        o[64]  = v;
        o[128] = v;
    }
}

extern "C" void kernel_launch(void* const* d_in, const int* in_sizes, int n_in,
                              void* d_out, int out_size, void* d_ws, size_t ws_size,
                              hipStream_t stream) {
    const float* x   = (const float*)d_in[0];
    float*       out = (float*)d_out;
    const int rows  = in_sizes[0] / 4;                       // 65536
    const int waves = (rows + ROWS_PER_WAVE - 1) / ROWS_PER_WAVE;  // 8192
    const int blocks = (waves * 64 + 255) / 256;             // 2048
    nerf_pe_kernel<<<blocks, 256, 0, stream>>>(x, out, rows);
}